// Round 8
// baseline (324.549 us; speedup 1.0000x reference)
//
#include <hip/hip_runtime.h>
#include <math.h>

// Problem constants (from reference)
#define B_ 16
#define T_ 4096
#define C_ 512
#define E_ 64
#define K_ 2048
#define N_ (B_*T_)          // 65536
#define ZQ_ELEMS 4194304    // B*E*T

typedef __attribute__((ext_vector_type(8))) short short8;
typedef __attribute__((ext_vector_type(4))) short short4v;
typedef __attribute__((ext_vector_type(4))) float f32x4;

// ws layout (bytes):
//   ehi_sw : [16][8192] bf16 B-frag-tiled codebook hi @ 0       (256 KB)
//   elo_sw : lo plane                              @ 262144     (256 KB)
//   nhcc   : [K] f32 (-0.5*||e_k||^2)              @ 524288     (8 KB)
//   w_hi   : [64][512] bf16                        @ 532480     (64 KB)
//   w_lo   : [64][512] bf16                        @ 598016     (64 KB)
//   hist   : [K] i32                               @ 663552     (8 KB)  <- memset w/ loss
//   loss   : f32                                   @ 671744     (4 B)
//   himg   : [512 groups][16384] shorts (hi 8192 | lo 8192) @ 1 MB (16.78 MB)
#define WS_EHI   0
#define WS_ELO   262144
#define WS_NHCC  524288
#define WS_WHI   532480
#define WS_WLO   598016
#define WS_HIST  663552
#define WS_LOSS  671744
#define WS_HIMG  1048576
#define WS_NEED  (WS_HIMG + 512*16384*2)   // ~17.8 MB

struct HiLo { short hi, lo; };

__device__ __forceinline__ unsigned short rne16(float v) {
    unsigned u = __float_as_uint(v);
    return (unsigned short)((u + 0x7FFFu + ((u >> 16) & 1u)) >> 16);
}
__device__ __forceinline__ HiLo split_rne(float v) {
    HiLo r;
    unsigned hb = rne16(v);
    r.hi = (short)hb;
    float hf = __uint_as_float((unsigned)hb << 16);
    r.lo = (short)rne16(v - hf);
    return r;
}

// Async global->LDS, 16B per lane (used by the fused fallback only).
typedef const __attribute__((address_space(1))) void* gas1_t;
typedef __attribute__((address_space(3))) void* las3_t;
__device__ __forceinline__ void gl16(const void* g, void* l) {
    __builtin_amdgcn_global_load_lds((gas1_t)g, (las3_t)l, 16, 0, 0);
}

// ---------------------------------------------------------------------------
// Prep. Blocks 0..63: embed -> B-frag-tiled bf16 hi/lo + nhcc.
//       Blocks 64..95: W -> flat bf16 hi/lo.
// Tiled layout per 128-k chunk (8192 shorts/plane): slot for (r=k&127, e):
//   kt=r>>4, col=r&15, ks=e>>5, qe=(e>>3)&3 -> ((kt*2+ks)*64 + qe*16 + col)*8 + (e&7)
// so a vq wave's B-frag read (pb + lane*8) is a coalesced 1 KB run directly
// from global (L2-resident).
// ---------------------------------------------------------------------------
__global__ void prep_kernel(const float* __restrict__ embed,
                            const float* __restrict__ W,
                            short* __restrict__ ehi, short* __restrict__ elo,
                            float* __restrict__ nhcc,
                            short* __restrict__ whi, short* __restrict__ wlo) {
    const int tid = threadIdx.x;
    if (blockIdx.x < 64) {
        const int row = blockIdx.x * 32 + (tid >> 3);
        const int g = tid & 7;
        const float* src = embed + (size_t)row * 64 + g * 8;
        short8 hv, lv;
        float s = 0.f;
#pragma unroll
        for (int j = 0; j < 8; ++j) {
            float v = src[j];
            s = fmaf(v, v, s);
            HiLo r = split_rne(v);
            hv[j] = r.hi; lv[j] = r.lo;
        }
        const int c128 = row >> 7, r = row & 127;
        const int kt = r >> 4, col = r & 15, ks = g >> 2, qe = g & 3;
        const int slot = (kt * 2 + ks) * 64 + qe * 16 + col;
        *(short8*)(ehi + c128 * 8192 + slot * 8) = hv;
        *(short8*)(elo + c128 * 8192 + slot * 8) = lv;
        s += __shfl_xor(s, 1, 64);
        s += __shfl_xor(s, 2, 64);
        s += __shfl_xor(s, 4, 64);
        if (g == 0) nhcc[row] = -0.5f * s;
    } else {
        int idx = ((blockIdx.x - 64) * 256 + tid) * 4;
        float4 v = *(const float4*)(W + idx);
        short4v h, l;
        HiLo a = split_rne(v.x); h[0] = a.hi; l[0] = a.lo;
        HiLo b = split_rne(v.y); h[1] = b.hi; l[1] = b.lo;
        HiLo c = split_rne(v.z); h[2] = c.hi; l[2] = c.lo;
        HiLo d = split_rne(v.w); h[3] = d.hi; l[3] = d.lo;
        *(short4v*)(whi + idx) = h;
        *(short4v*)(wlo + idx) = l;
    }
}

// ---------------------------------------------------------------------------
// proj_kernel v5: c-split waves + PER-BLOCK C-CHUNK STAGGER.
// All 512 blocks read the SAME W in the same order -> L2 bank hotspot.
// Chunk order ce = (it + blk) & 7 decorrelates the W address stream mod 8
// (c-halves differ too). Only changes f32 accumulation order (ulp noise,
// dominated by the existing bf16-split perturbation).
// Block covers 128 t: 2 t-tiles (tl) x 2 c-halves (cs); 256-B-segment x
// loads + wave-private-LDS transpose (barrier-free loop); f32 merge. Grid 512.
// ---------------------------------------------------------------------------
__global__ __launch_bounds__(256, 2) void proj_kernel(
        const float* __restrict__ x,
        const short* __restrict__ whi, const short* __restrict__ wlo,
        const float* __restrict__ bias,
        short* __restrict__ himg, float* __restrict__ lossacc) {
    __shared__ __align__(16) float xw[4 * 32 * 66];   // loop: wave-private [32][66]
                                                      // merge: [2][64][66]
    const int tid = threadIdx.x;
    const int wave = tid >> 6, lane = tid & 63;
    const int row16 = lane & 15, quad = lane >> 4;
    const int blk = blockIdx.x;            // 512 blocks, 128 t each
    const int b  = blk >> 5;
    const int t0 = (blk & 31) * 128;
    const int tl = wave & 1;               // t-tile (64 t) within block
    const int cs = wave >> 1;              // c-half
    const int t0w = t0 + tl * 64;
    const float* xr = x + (size_t)b * C_ * T_ + t0w;
    float* wl = xw + wave * (32 * 66);

    const int c_row = lane >> 4;           // 0..3
    const int c_t4  = (lane & 15) * 4;     // 16 lanes x float4 = 256-B segment
    const int cbase = cs * 256;
    const int boff  = blk & 7;             // stagger phase

    f32x4 acc[4][4];
#pragma unroll
    for (int rt = 0; rt < 4; ++rt)
#pragma unroll
        for (int et = 0; et < 4; ++et) acc[rt][et] = (f32x4){0.f, 0.f, 0.f, 0.f};

    float4 xn[8];
#pragma unroll
    for (int q = 0; q < 8; ++q)
        xn[q] = *(const float4*)(xr + (size_t)(cbase + boff * 32 + q * 4 + c_row) * T_ + c_t4);

    for (int it = 0; it < 8; ++it) {
        const int ce = (it + boff) & 7;    // this iteration's chunk
        const int c0 = cbase + ce * 32;
        // park chunk into private LDS
#pragma unroll
        for (int q = 0; q < 8; ++q) {
            float* d = wl + (q * 4 + c_row) * 66 + c_t4;
            *(float2*)(d)     = make_float2(xn[q].x, xn[q].y);
            *(float2*)(d + 2) = make_float2(xn[q].z, xn[q].w);
        }
        if (it < 7) {
            const int cn = cbase + ((it + 1 + boff) & 7) * 32;
#pragma unroll
            for (int q = 0; q < 8; ++q)
                xn[q] = *(const float4*)(xr + (size_t)(cn + q * 4 + c_row) * T_ + c_t4);
        }
#pragma unroll
        for (int rp = 0; rp < 2; ++rp) {
            short8 bh[2], bl[2];
#pragma unroll
            for (int rr = 0; rr < 2; ++rr) {
                const int rt = rp * 2 + rr;
#pragma unroll
                for (int j = 0; j < 8; ++j) {
                    float v = wl[(quad * 8 + j) * 66 + rt * 16 + row16];
                    HiLo r = split_rne(v);
                    bh[rr][j] = r.hi; bl[rr][j] = r.lo;
                }
            }
#pragma unroll
            for (int et = 0; et < 4; ++et) {
                size_t aoff = (size_t)(et * 16 + row16) * C_ + c0 + quad * 8;
                short8 ah = *(const short8*)(whi + aoff);
                short8 al = *(const short8*)(wlo + aoff);
#pragma unroll
                for (int rr = 0; rr < 2; ++rr) {
                    const int rt = rp * 2 + rr;
                    acc[rt][et] = __builtin_amdgcn_mfma_f32_16x16x32_bf16(ah, bh[rr], acc[rt][et], 0, 0, 0);
                    acc[rt][et] = __builtin_amdgcn_mfma_f32_16x16x32_bf16(al, bh[rr], acc[rt][et], 0, 0, 0);
                    acc[rt][et] = __builtin_amdgcn_mfma_f32_16x16x32_bf16(ah, bl[rr], acc[rt][et], 0, 0, 0);
                    acc[rt][et] = __builtin_amdgcn_mfma_f32_16x16x32_bf16(al, bl[rr], acc[rt][et], 0, 0, 0);
                }
            }
        }
    }

    // ---- merge the two c-halves (f32) through LDS [2][64][66] ----
    __syncthreads();                        // everyone done with private xw
    if (cs == 1) {
#pragma unroll
        for (int rt = 0; rt < 4; ++rt)
#pragma unroll
            for (int et = 0; et < 4; ++et)
#pragma unroll
                for (int r = 0; r < 4; ++r)
                    xw[(tl * 64 + et * 16 + quad * 4 + r) * 66 + rt * 16 + row16] =
                        acc[rt][et][r];
    }
    __syncthreads();
    if (cs == 0) {
#pragma unroll
        for (int rt = 0; rt < 4; ++rt)
#pragma unroll
            for (int et = 0; et < 4; ++et)
#pragma unroll
                for (int r = 0; r < 4; ++r)
                    acc[rt][et][r] +=
                        xw[(tl * 64 + et * 16 + quad * 4 + r) * 66 + rt * 16 + row16];

        // Epilogue: bias, ||h||^2, store h hi/lo in A-frag order to himg.
        // himg group g = blk (128 rows); 16-t tile w2 = tl*4 + rt.
        short* gb = himg + (size_t)blk * 16384;
        float hh = 0.f;
#pragma unroll
        for (int rt = 0; rt < 4; ++rt) {
            const int w2 = tl * 4 + rt;
#pragma unroll
            for (int et = 0; et < 4; ++et) {
                float4 bv = *(const float4*)(bias + et * 16 + quad * 4);
                f32x4 a = acc[rt][et];
                a[0] += bv.x; a[1] += bv.y; a[2] += bv.z; a[3] += bv.w;
                hh = fmaf(a[0], a[0], hh); hh = fmaf(a[1], a[1], hh);
                hh = fmaf(a[2], a[2], hh); hh = fmaf(a[3], a[3], hh);
                short4v hv, lv;
#pragma unroll
                for (int r = 0; r < 4; ++r) {
                    HiLo sp = split_rne(a[r]);
                    hv[r] = sp.hi; lv[r] = sp.lo;
                }
                const int ks = et >> 1;
                const int qe = (et & 1) * 2 + (quad >> 1);
                const int j0 = (quad & 1) * 4;
                const int sl = ((w2 * 2 + ks) * 64 + qe * 16 + row16) * 8 + j0;
                *(short4v*)(gb + sl) = hv;
                *(short4v*)(gb + 8192 + sl) = lv;
            }
        }
#pragma unroll
        for (int m = 1; m < 64; m <<= 1) hh += __shfl_xor(hh, m, 64);
        if (lane == 0) atomicAdd(lossacc, hh);
    }
}

// ---------------------------------------------------------------------------
// vq_kernel v7: round-7 structure + PER-BLOCK SCAN STAGGER.
// All 4096 waves read the same 512 KB codebook in the same order -> L2 bank
// hotspot (the prime suspect for the occupancy-invariant 79 us). Each block
// starts its scan at phase (g2 & 15)*2 and wraps. In-loop tie-break
// (v==vmax && kk<vidx) keeps the argmax scan-order-invariant -> bit-identical.
// Block = (group, rowgrp) -> 64 rows; 4 waves = 4 kh quarters, 32 steps x
// 24 MFMA, dbuf direct-from-L2 B loads. Grid 1024, launch_bounds(256,2)
// (128-reg budget; VGPR ~92, no spill).
// ---------------------------------------------------------------------------
#define VQ_STEP(H0, H1, L0, L1, SS)                                            \
    {                                                                          \
        const int ss_ = (SS);                                                  \
        const int kk = (ss_ >> 1) * 128 + (kh * 2 + (ss_ & 1)) * 16 + row16;   \
        const float ci = nhcc[kk];                                             \
        _Pragma("unroll")                                                      \
        for (int rt = 0; rt < 4; ++rt) {                                       \
            f32x4 a2 = (f32x4){0.f, 0.f, 0.f, 0.f};                            \
            a2 = __builtin_amdgcn_mfma_f32_16x16x32_bf16(a_hi[rt][0], H0, a2, 0, 0, 0); \
            a2 = __builtin_amdgcn_mfma_f32_16x16x32_bf16(a_hi[rt][1], H1, a2, 0, 0, 0); \
            a2 = __builtin_amdgcn_mfma_f32_16x16x32_bf16(a_lo[rt][0], H0, a2, 0, 0, 0); \
            a2 = __builtin_amdgcn_mfma_f32_16x16x32_bf16(a_lo[rt][1], H1, a2, 0, 0, 0); \
            a2 = __builtin_amdgcn_mfma_f32_16x16x32_bf16(a_hi[rt][0], L0, a2, 0, 0, 0); \
            a2 = __builtin_amdgcn_mfma_f32_16x16x32_bf16(a_hi[rt][1], L1, a2, 0, 0, 0); \
            _Pragma("unroll")                                                  \
            for (int rg = 0; rg < 4; ++rg) {                                   \
                float v = a2[rg] + ci;                                         \
                if (v > vmax[rt][rg] ||                                        \
                    (v == vmax[rt][rg] && kk < vidx[rt][rg])) {                \
                    vmax[rt][rg] = v; vidx[rt][rg] = kk;                       \
                }                                                              \
            }                                                                  \
        }                                                                      \
    }

#define VQ_LOAD(H0, H1, L0, L1, SS)                                            \
    {                                                                          \
        const int sl_ = (SS);                                                  \
        const int c2 = sl_ >> 1, kt2 = kh * 2 + (sl_ & 1);                     \
        const short* pb = ehi + c2 * 8192 + kt2 * 1024;                        \
        const short* pl = elo + c2 * 8192 + kt2 * 1024;                        \
        H0 = *(const short8*)(pb + lane * 8);                                  \
        H1 = *(const short8*)(pb + 512 + lane * 8);                            \
        L0 = *(const short8*)(pl + lane * 8);                                  \
        L1 = *(const short8*)(pl + 512 + lane * 8);                            \
    }

__global__ __launch_bounds__(256, 2) void vq_kernel(
        const short* __restrict__ himg,
        const short* __restrict__ ehi, const short* __restrict__ elo,
        const float* __restrict__ nhcc,
        const float* __restrict__ embed, float* __restrict__ out,
        int* __restrict__ hist, float* __restrict__ lossacc) {
    __shared__ __align__(16) float tile[64 * 69];    // 17664 B (gather)
    __shared__ int   qsm[64];
    __shared__ float vtmp[3 * 64];
    __shared__ int   itmp[3 * 64];

    const int tid = threadIdx.x;
    const int kh = tid >> 6, lane = tid & 63;        // wave index = kh quarter
    const int row16 = lane & 15, quad = lane >> 4;
    const int g2 = blockIdx.x;                       // 1024 blocks
    const int g  = g2 >> 1;                          // himg group (128 rows)
    const int rowgrp = g2 & 1;                       // which 64 rows
    const int b  = g >> 5;
    const int t0 = (g & 31) * 128 + rowgrp * 64;
    const int soff = (g2 & 15) * 2;                  // stagger phase (even)

    // A-frags: lane-linear from global h-image (4 rt x 2 ks, hi+lo).
    const short* gb = himg + (size_t)g * 16384;
    short8 a_hi[4][2], a_lo[4][2];
#pragma unroll
    for (int rt = 0; rt < 4; ++rt)
#pragma unroll
        for (int ks = 0; ks < 2; ++ks) {
            const int w2 = rowgrp * 4 + rt;
            const int sl = ((w2 * 2 + ks) * 64 + lane) * 8;
            a_hi[rt][ks] = *(const short8*)(gb + sl);
            a_lo[rt][ks] = *(const short8*)(gb + 8192 + sl);
        }

    float vmax[4][4];
    int   vidx[4][4];
#pragma unroll
    for (int rt = 0; rt < 4; ++rt)
#pragma unroll
        for (int rg = 0; rg < 4; ++rg) { vmax[rt][rg] = -3.4e38f; vidx[rt][rg] = 0; }

    short8 pAh0, pAh1, pAl0, pAl1;
    short8 pBh0, pBh1, pBl0, pBl1;
    VQ_LOAD(pAh0, pAh1, pAl0, pAl1, soff);
    for (int s = 0; s < 32; s += 2) {
        VQ_LOAD(pBh0, pBh1, pBl0, pBl1, (s + 1 + soff) & 31);
        VQ_STEP(pAh0, pAh1, pAl0, pAl1, (s + soff) & 31);
        if (s + 2 < 32) VQ_LOAD(pAh0, pAh1, pAl0, pAl1, (s + 2 + soff) & 31);
        VQ_STEP(pBh0, pBh1, pBl0, pBl1, (s + 1 + soff) & 31);
    }

    // 16-lane k-reduce (tie -> lowest idx), then 4-way kh merge via LDS.
    float s_loss = 0.f;
#pragma unroll
    for (int rt = 0; rt < 4; ++rt)
#pragma unroll
        for (int rg = 0; rg < 4; ++rg) {
            float v = vmax[rt][rg];
            int ix = vidx[rt][rg];
#pragma unroll
            for (int m = 1; m < 16; m <<= 1) {
                float ov = __shfl_xor(v, m, 64);
                int   oi = __shfl_xor(ix, m, 64);
                if (ov > v || (ov == v && oi < ix)) { v = ov; ix = oi; }
            }
            vmax[rt][rg] = v; vidx[rt][rg] = ix;
        }
    if (kh >= 1 && row16 == 0) {
#pragma unroll
        for (int rt = 0; rt < 4; ++rt)
#pragma unroll
            for (int rg = 0; rg < 4; ++rg) {
                const int row = rt * 16 + quad * 4 + rg;   // local 0..63
                vtmp[(kh - 1) * 64 + row] = vmax[rt][rg];
                itmp[(kh - 1) * 64 + row] = vidx[rt][rg];
            }
    }
    __syncthreads();
    if (kh == 0) {
        if (row16 == 0) {
#pragma unroll
            for (int rt = 0; rt < 4; ++rt)
#pragma unroll
                for (int rg = 0; rg < 4; ++rg) {
                    const int row = rt * 16 + quad * 4 + rg;
                    float v = vmax[rt][rg];
                    int ix = vidx[rt][rg];
#pragma unroll
                    for (int p = 0; p < 3; ++p) {
                        const float ov = vtmp[p * 64 + row];
                        const int   oi = itmp[p * 64 + row];
                        if (ov > v || (ov == v && oi < ix)) { v = ov; ix = oi; }
                    }
                    qsm[row] = ix;
                    atomicAdd(&hist[ix], 1);
                    s_loss += v;
                }
        }
        s_loss += __shfl_xor(s_loss, 16, 64);
        s_loss += __shfl_xor(s_loss, 32, 64);
        if (lane == 0) atomicAdd(lossacc, -2.f * s_loss);
    }
    __syncthreads();

    // ---------------- Fused gather + transpose (64 rows) ----------------
    {
        const int r = tid >> 2, piece = tid & 3;
        const float* src = embed + (size_t)qsm[r] * 64 + piece * 16;
        float* dst = tile + r * 69 + piece * 16;
#pragma unroll
        for (int j = 0; j < 4; ++j)
            *(float4*)(dst + j * 4) = *(const float4*)(src + j * 4);
    }
    __syncthreads();
    {
        const int tt = tid & 63;
        const int eo = tid >> 6;               // 0..3
        float* ob = out + ((size_t)b * 64) * T_ + t0;
#pragma unroll
        for (int j = 0; j < 16; ++j) {
            const int e = j * 4 + eo;
            ob[(size_t)e * T_ + tt] = tile[tt * 69 + e];
        }
    }
}

// ---------------------------------------------------------------------------
// Fused fallback (verified round-1 kernel) — used only if ws is too small
// for the h-image.
// ---------------------------------------------------------------------------
__global__ __launch_bounds__(512, 4) void projvq_kernel(
        const float* __restrict__ x,
        const short* __restrict__ whi, const short* __restrict__ wlo,
        const float* __restrict__ bias,
        const short* __restrict__ ehi, const short* __restrict__ elo,
        const float* __restrict__ nhcc,
        const float* __restrict__ embed, float* __restrict__ out,
        int* __restrict__ hist, float* __restrict__ lossacc) {
    __shared__ __align__(16) char smem[68096];
    float* xsf  = (float*)smem;
    short* es   = (short*)smem;
    short* aimg = (short*)(smem + 32768);
    float* ccs  = (float*)(smem + 65536);
    int*   qsm2 = (int*)(smem + 66560);
    float* vtmp = (float*)(smem + 67072);
    int*   itmp = (int*)(smem + 67584);
    float* tile = (float*)smem;

    const int tid = threadIdx.x;
    const int wave = tid >> 6, lane = tid & 63;
    const int row16 = lane & 15, quad = lane >> 4;
    const int b  = blockIdx.x >> 5;
    const int t0 = (blockIdx.x & 31) * 128;
    const float* xb = x + (size_t)b * C_ * T_ + t0;

    f32x4 cc = *(const f32x4*)(nhcc + tid * 4);

    f32x4 acc[4];
#pragma unroll
    for (int et = 0; et < 4; ++et) acc[et] = (f32x4){0.f, 0.f, 0.f, 0.f};

#pragma unroll
    for (int j = 0; j < 2; ++j) {
        int o = j * 512 + tid;
        gl16(xb + (size_t)(o >> 5) * T_ + (o & 31) * 4, xsf + o * 4);
    }
    __syncthreads();

    for (int it = 0; it < 16; ++it) {
        const int c0 = it * 32;
        const int p = it & 1;
        if (it < 15) {
#pragma unroll
            for (int j = 0; j < 2; ++j) {
                int o = j * 512 + tid;
                gl16(xb + (size_t)(c0 + 32 + (o >> 5)) * T_ + (o & 31) * 4,
                     xsf + (p ^ 1) * 4096 + o * 4);
            }
        }
        const float* xsb = xsf + p * 4096;
        short8 bh, bl;
#pragma unroll
        for (int j = 0; j < 8; ++j) {
            float v = xsb[(quad * 8 + j) * 128 + wave * 16 + row16];
            HiLo r = split_rne(v);
            bh[j] = r.hi; bl[j] = r.lo;
        }
#pragma unroll
        for (int et = 0; et < 4; ++et) {
            size_t aoff = (size_t)(et * 16 + row16) * C_ + c0 + quad * 8;
            short8 ah = *(const short8*)(whi + aoff);
            short8 al = *(const short8*)(wlo + aoff);
            acc[et] = __builtin_amdgcn_mfma_f32_16x16x32_bf16(ah, bh, acc[et], 0, 0, 0);
            acc[et] = __builtin_amdgcn_mfma_f32_16x16x32_bf16(al, bh, acc[et], 0, 0, 0);
            acc[et] = __builtin_amdgcn_mfma_f32_16x16x32_bf16(ah, bl, acc[et], 0, 0, 0);
            acc[et] = __builtin_amdgcn_mfma_f32_16x16x32_bf16(al, bl, acc[et], 0, 0, 0);
        }
        __syncthreads();
    }

#pragma unroll
    for (int j = 0; j < 2; ++j) {
        int o = (j * 512 + tid) * 8;
        gl16(ehi + o, es + o);
        gl16(elo + o, es + 8192 + o);
    }

    float hh = 0.f;
#pragma unroll
    for (int et = 0; et < 4; ++et) {
        float4 bv = *(const float4*)(bias + et * 16 + quad * 4);
        f32x4 a = acc[et];
        a[0] += bv.x; a[1] += bv.y; a[2] += bv.z; a[3] += bv.w;
        hh = fmaf(a[0], a[0], hh); hh = fmaf(a[1], a[1], hh);
        hh = fmaf(a[2], a[2], hh); hh = fmaf(a[3], a[3], hh);
        short4v hv, lv;
#pragma unroll
        for (int r = 0; r < 4; ++r) {
            HiLo sp = split_rne(a[r]);
            hv[r] = sp.hi; lv[r] = sp.lo;
        }
        const int ks = et >> 1;
        const int qe = (et & 1) * 2 + (quad >> 1);
        const int j0 = (quad & 1) * 4;
        const int sl = ((wave * 2 + ks) * 64 + qe * 16 + row16) * 8 + j0;
        *(short4v*)(aimg + sl) = hv;
        *(short4v*)(aimg + 8192 + sl) = lv;
    }
#pragma unroll
    for (int m = 1; m < 64; m <<= 1) hh += __shfl_xor(hh, m, 64);
    if (lane == 0) atomicAdd(lossacc, hh);
    __syncthreads();

    const int pair = wave & 3, kh = wave >> 2;
    short8 a_hi[2][2], a_lo[2][2];
#pragma unroll
    for (int rt = 0; rt < 2; ++rt)
#pragma unroll
        for (int ks = 0; ks < 2; ++ks) {
            int sl = (((2 * pair + rt) * 2 + ks) * 64 + lane) * 8;
            a_hi[rt][ks] = *(const short8*)(aimg + sl);
            a_lo[rt][ks] = *(const short8*)(aimg + 8192 + sl);
        }
    if ((tid >> 5) == 0) *(f32x4*)(ccs + (tid & 31) * 4) = cc;
    __syncthreads();

    float vmax[2][4];
    int   vidx[2][4];
#pragma unroll
    for (int rt = 0; rt < 2; ++rt)
#pragma unroll
        for (int rg = 0; rg < 4; ++rg) { vmax[rt][rg] = -3.4e38f; vidx[rt][rg] = 0; }

    for (int c = 0; c < 16; ++c) {
        if (c < 15) {
            const short* sh  = ehi + (c + 1) * 8192;
            const short* sl2 = elo + (c + 1) * 8192;
            short* dst = es + ((c + 1) & 1) * 16384;
#pragma unroll
            for (int j = 0; j < 2; ++j) {
                int o = (j * 512 + tid) * 8;
                gl16(sh + o, dst + o);
                gl16(sl2 + o, dst + 8192 + o);
            }
            if ((tid >> 5) == c + 1)
                *(f32x4*)(ccs + ((c + 1) & 1) * 128 + (tid & 31) * 4) = cc;
        }
        const short* eb = es + (c & 1) * 16384;
        const float* cb = ccs + (c & 1) * 128;
#pragma unroll
        for (int k4 = 0; k4 < 4; ++k4) {
            const int kt = kh * 4 + k4;
            const float ci = cb[kt * 16 + row16];
            const short* pb = eb + kt * 1024;
            short8 bh0 = *(const short8*)(pb + lane * 8);
            short8 bh1 = *(const short8*)(pb + 512 + lane * 8);
            short8 bl0 = *(const short8*)(pb + 8192 + lane * 8);
            short8 bl1 = *(const short8*)(pb + 8192 + 512 + lane * 8);
            const int kk = c * 128 + kt * 16 + row16;
#pragma unroll
            for (int rt = 0; rt < 2; ++rt) {
                f32x4 a2 = (f32x4){0.f, 0.f, 0.f, 0.f};
                a2 = __builtin_amdgcn_mfma_f32_16x16x32_bf16(a_hi[rt][0], bh0, a2, 0, 0, 0);
                a2 = __builtin_amdgcn_mfma_f32_16x16x32_bf16(a_hi[rt][1], bh1, a2, 0, 0, 0);
                a2 = __builtin_amdgcn_mfma_f32_16x16x32_bf16(a_lo[rt][0], bh0, a2, 0, 0, 0);
                a2 = __builtin_amdgcn_mfma_f32_16x16x32_bf16(a_lo[rt][1], bh1, a2, 0, 0, 0);
                a2 = __builtin_amdgcn_mfma_f32_16x16x32_bf16(a_hi[rt][0], bl0, a2, 0, 0, 0);
                a2 = __builtin_amdgcn_mfma_f32_16x16x32_bf16(a_hi[rt][1], bl1, a2, 0, 0, 0);
#pragma unroll
                for (int rg = 0; rg < 4; ++rg) {
                    float v = a2[rg] + ci;
                    if (v > vmax[rt][rg]) { vmax[rt][rg] = v; vidx[rt][rg] = kk; }
                }
            }
        }
        __syncthreads();
    }

    float s = 0.f;
#pragma unroll
    for (int rt = 0; rt < 2; ++rt)
#pragma unroll
        for (int rg = 0; rg < 4; ++rg) {
            float v = vmax[rt][rg];
            int ix = vidx[rt][rg];
#pragma unroll
            for (int m = 1; m < 16; m <<= 1) {
                float ov = __shfl_xor(v, m, 64);
                int   oi = __shfl_xor(ix, m, 64);
                if (ov > v || (ov == v && oi < ix)) { v = ov; ix = oi; }
            }
            vmax[rt][rg] = v; vidx[rt][rg] = ix;
        }
    if (kh == 1 && row16 == 0) {
#pragma unroll
        for (int rt = 0; rt < 2; ++rt)
#pragma unroll
            for (int rg = 0; rg < 4; ++rg) {
                const int row = (2 * pair + rt) * 16 + quad * 4 + rg;
                vtmp[row] = vmax[rt][rg];
                itmp[row] = vidx[rt][rg];
            }
    }
    __syncthreads();
    if (kh == 0) {
        if (row16 == 0) {
#pragma unroll
            for (int rt = 0; rt < 2; ++rt)
#pragma unroll
                for (int rg = 0; rg < 4; ++rg) {
                    const int row = (2 * pair + rt) * 16 + quad * 4 + rg;
                    float v = vmax[rt][rg];
                    int ix = vidx[rt][rg];
                    const float ov = vtmp[row];
                    const int   oi = itmp[row];
                    if (ov > v || (ov == v && oi < ix)) { v = ov; ix = oi; }
                    qsm2[row] = ix;
                    atomicAdd(&hist[ix], 1);
                    s += v;
                }
        }
        s += __shfl_xor(s, 16, 64);
        s += __shfl_xor(s, 32, 64);
        if (lane == 0) atomicAdd(lossacc, -2.f * s);
    }
    __syncthreads();

    {
        const int r = tid >> 2, piece = tid & 3;
        const float* src = embed + (size_t)qsm2[r] * 64 + piece * 16;
        float* dst = tile + r * 69 + piece * 16;
#pragma unroll
        for (int j = 0; j < 4; ++j)
            *(float4*)(dst + j * 4) = *(const float4*)(src + j * 4);
    }
    __syncthreads();
    {
        const int tt = tid & 63;
        const int eo = tid >> 6;
#pragma unroll
        for (int j = 0; j < 8; ++j) {
            const int e = j * 8 + eo;
            float* ob = out + ((size_t)b * 64) * T_ + t0;
            ob[(size_t)e * T_ + tt]      = tile[tt * 69 + e];
            ob[(size_t)e * T_ + 64 + tt] = tile[(tt + 64) * 69 + e];
        }
    }
}

// ---------------------------------------------------------------------------
// Finalize: loss, kldiv constant, log-perplexity.
// ---------------------------------------------------------------------------
__global__ void finalize_kernel(const int* __restrict__ hist,
                                const float* __restrict__ lossacc,
                                float* __restrict__ out) {
    __shared__ float red[4];
    const int tid = threadIdx.x;
    float s = 0.f;
    for (int k = tid; k < K_; k += 256) {
        float p = (float)hist[k] * (1.f / 65536.f);
        s -= p * logf(p + 1e-10f);
    }
#pragma unroll
    for (int m = 1; m < 64; m <<= 1) s += __shfl_xor(s, m, 64);
    if ((tid & 63) == 0) red[tid >> 6] = s;
    __syncthreads();
    if (tid == 0) {
        float lp = red[0] + red[1] + red[2] + red[3];
        out[ZQ_ELEMS] = 0.25f * lossacc[0] / (float)ZQ_ELEMS;    // loss
        out[ZQ_ELEMS + 17] = lp;                                  // log_perplexity
    }
    if (tid < 16) out[ZQ_ELEMS + 1 + tid] = logf(2048.f) * 4096.f;  // kldiv_r
}

// ---------------------------------------------------------------------------
extern "C" void kernel_launch(void* const* d_in, const int* in_sizes, int n_in,
                              void* d_out, int out_size, void* d_ws, size_t ws_size,
                              hipStream_t stream) {
    const float* x      = (const float*)d_in[0];
    const float* proj_w = (const float*)d_in[1];
    const float* proj_b = (const float*)d_in[2];
    const float* embed  = (const float*)d_in[3];
    float* out = (float*)d_out;
    char* ws = (char*)d_ws;

    short* e_hi = (short*)(ws + WS_EHI);
    short* e_lo = (short*)(ws + WS_ELO);
    float* nhcc = (float*)(ws + WS_NHCC);
    short* w_hi = (short*)(ws + WS_WHI);
    short* w_lo = (short*)(ws + WS_WLO);
    int*   hist = (int*)(ws + WS_HIST);
    float* lossac = (float*)(ws + WS_LOSS);
    short* himg = (short*)(ws + WS_HIMG);

    // hist + loss adjacent; zero both (ws poisoned 0xAA each launch).
    (void)hipMemsetAsync(ws + WS_HIST, 0, K_ * sizeof(int) + sizeof(float), stream);

    prep_kernel<<<96, 256, 0, stream>>>(embed, proj_w, e_hi, e_lo, nhcc, w_hi, w_lo);
    if (ws_size >= (size_t)WS_NEED) {
        proj_kernel<<<512, 256, 0, stream>>>(x, w_hi, w_lo, proj_b, himg, lossac);
        vq_kernel<<<1024, 256, 0, stream>>>(himg, e_hi, e_lo, nhcc, embed, out,
                                            hist, lossac);
    } else {
        projvq_kernel<<<N_ / 128, 512, 0, stream>>>(x, w_hi, w_lo, proj_b,
                                                    e_hi, e_lo, nhcc, embed, out,
                                                    hist, lossac);
    }
    finalize_kernel<<<1, 256, 0, stream>>>(hist, lossac, out);
}

// Round 9
// 271.344 us; speedup vs baseline: 1.1961x; 1.1961x over previous
//
#include <hip/hip_runtime.h>
#include <math.h>

// Problem constants (from reference)
#define B_ 16
#define T_ 4096
#define C_ 512
#define E_ 64
#define K_ 2048
#define N_ (B_*T_)          // 65536
#define ZQ_ELEMS 4194304    // B*E*T

typedef __attribute__((ext_vector_type(8))) short short8;
typedef __attribute__((ext_vector_type(4))) short short4v;
typedef __attribute__((ext_vector_type(4))) float f32x4;

// ws layout (bytes):
//   ehi_sw : [16][8192] bf16 B-frag-tiled codebook hi @ 0       (256 KB)
//   elo_sw : lo plane                              @ 262144     (256 KB)
//   nhcc   : [K] f32 (-0.5*||e_k||^2)              @ 524288     (8 KB)
//   w_hi   : [64][512] bf16                        @ 532480     (64 KB)
//   w_lo   : [64][512] bf16                        @ 598016     (64 KB)
//   hist   : [K] i32                               @ 663552     (8 KB)  <- zeroed by prep
//   loss   : f32                                   @ 671744     (4 B)
#define WS_EHI   0
#define WS_ELO   262144
#define WS_NHCC  524288
#define WS_WHI   532480
#define WS_WLO   598016
#define WS_HIST  663552
#define WS_LOSS  671744

struct HiLo { short hi, lo; };

__device__ __forceinline__ unsigned short rne16(float v) {
    unsigned u = __float_as_uint(v);
    return (unsigned short)((u + 0x7FFFu + ((u >> 16) & 1u)) >> 16);
}
__device__ __forceinline__ HiLo split_rne(float v) {
    HiLo r;
    unsigned hb = rne16(v);
    r.hi = (short)hb;
    float hf = __uint_as_float((unsigned)hb << 16);
    r.lo = (short)rne16(v - hf);
    return r;
}

// ---------------------------------------------------------------------------
// Prep. Blocks 0..63: embed -> B-frag-tiled bf16 hi/lo + nhcc.
//       Blocks 64..95: W -> flat bf16 hi/lo.
//       Block 0 additionally zeroes hist+loss (replaces the memset dispatch;
//       stream order guarantees completion before the fused kernel).
// Tiled layout per 128-k chunk (8192 shorts/plane): slot for (r=k&127, e):
//   kt=r>>4, col=r&15, ks=e>>5, qe=(e>>3)&3 -> ((kt*2+ks)*64 + qe*16 + col)*8 + (e&7)
// so a scan wave's B-frag read (pb + lane*8) is a coalesced 1 KB run directly
// from global (L2-resident).
// ---------------------------------------------------------------------------
__global__ void prep_kernel(const float* __restrict__ embed,
                            const float* __restrict__ W,
                            short* __restrict__ ehi, short* __restrict__ elo,
                            float* __restrict__ nhcc,
                            short* __restrict__ whi, short* __restrict__ wlo,
                            int* __restrict__ hist) {
    const int tid = threadIdx.x;
    if (blockIdx.x == 0) {
        for (int i = tid; i < K_ + 1; i += 256) hist[i] = 0;   // hist + loss word
    }
    if (blockIdx.x < 64) {
        const int row = blockIdx.x * 32 + (tid >> 3);
        const int g = tid & 7;
        const float* src = embed + (size_t)row * 64 + g * 8;
        short8 hv, lv;
        float s = 0.f;
#pragma unroll
        for (int j = 0; j < 8; ++j) {
            float v = src[j];
            s = fmaf(v, v, s);
            HiLo r = split_rne(v);
            hv[j] = r.hi; lv[j] = r.lo;
        }
        const int c128 = row >> 7, r = row & 127;
        const int kt = r >> 4, col = r & 15, ks = g >> 2, qe = g & 3;
        const int slot = (kt * 2 + ks) * 64 + qe * 16 + col;
        *(short8*)(ehi + c128 * 8192 + slot * 8) = hv;
        *(short8*)(elo + c128 * 8192 + slot * 8) = lv;
        s += __shfl_xor(s, 1, 64);
        s += __shfl_xor(s, 2, 64);
        s += __shfl_xor(s, 4, 64);
        if (g == 0) nhcc[row] = -0.5f * s;
    } else {
        int idx = ((blockIdx.x - 64) * 256 + tid) * 4;
        float4 v = *(const float4*)(W + idx);
        short4v h, l;
        HiLo a = split_rne(v.x); h[0] = a.hi; l[0] = a.lo;
        HiLo b = split_rne(v.y); h[1] = b.hi; l[1] = b.lo;
        HiLo c = split_rne(v.z); h[2] = c.hi; l[2] = c.lo;
        HiLo d = split_rne(v.w); h[3] = d.hi; l[3] = d.lo;
        *(short4v*)(whi + idx) = h;
        *(short4v*)(wlo + idx) = l;
    }
}

// ---------------------------------------------------------------------------
// Fused proj+VQ kernel. Block = 64 t-rows, 4 waves, grid 1024 (B*T/64).
// Phase 1: 4-way c-split projection. Each wave owns 128 c: 256-B-segment x
//   loads + wave-private LDS transpose (barrier-free), MFMA acc[4 rt][4 et].
//   Tree-merge partials in f32 via LDS; wave 0 adds bias, computes ||h||^2,
//   splits to bf16 hi/lo and parks the h A-frag image IN LDS (no himg).
// Phase 2: r7 scan structure. kh = wave (4 quarters), 32 steps x 24 MFMA,
//   double-buffered direct-from-L2 codebook loads; 4-way argmax merge;
//   fused gather + transpose.
// Blocks are fully independent -> phase-1 VMEM overlaps phase-2 MFMA/VALU
// across resident blocks (4/CU at 36.6 KB LDS, VGPR <= 128 via (256,2)).
// ---------------------------------------------------------------------------
#define VQ_STEP(H0, H1, L0, L1, SS)                                            \
    {                                                                          \
        const int kk = ((SS) >> 1) * 128 + (kh * 2 + ((SS) & 1)) * 16 + row16; \
        const float ci = nhcc[kk];                                             \
        _Pragma("unroll")                                                      \
        for (int rt = 0; rt < 4; ++rt) {                                       \
            f32x4 a2 = (f32x4){0.f, 0.f, 0.f, 0.f};                            \
            a2 = __builtin_amdgcn_mfma_f32_16x16x32_bf16(a_hi[rt][0], H0, a2, 0, 0, 0); \
            a2 = __builtin_amdgcn_mfma_f32_16x16x32_bf16(a_hi[rt][1], H1, a2, 0, 0, 0); \
            a2 = __builtin_amdgcn_mfma_f32_16x16x32_bf16(a_lo[rt][0], H0, a2, 0, 0, 0); \
            a2 = __builtin_amdgcn_mfma_f32_16x16x32_bf16(a_lo[rt][1], H1, a2, 0, 0, 0); \
            a2 = __builtin_amdgcn_mfma_f32_16x16x32_bf16(a_hi[rt][0], L0, a2, 0, 0, 0); \
            a2 = __builtin_amdgcn_mfma_f32_16x16x32_bf16(a_hi[rt][1], L1, a2, 0, 0, 0); \
            _Pragma("unroll")                                                  \
            for (int rg = 0; rg < 4; ++rg) {                                   \
                float v = a2[rg] + ci;                                         \
                if (v > vmax[rt][rg]) { vmax[rt][rg] = v; vidx[rt][rg] = kk; } \
            }                                                                  \
        }                                                                      \
    }

#define VQ_LOAD(H0, H1, L0, L1, SS)                                            \
    {                                                                          \
        const int c2 = (SS) >> 1, kt2 = kh * 2 + ((SS) & 1);                   \
        const short* pb = ehi + c2 * 8192 + kt2 * 1024;                        \
        const short* pl = elo + c2 * 8192 + kt2 * 1024;                        \
        H0 = *(const short8*)(pb + lane * 8);                                  \
        H1 = *(const short8*)(pb + 512 + lane * 8);                            \
        L0 = *(const short8*)(pl + lane * 8);                                  \
        L1 = *(const short8*)(pl + 512 + lane * 8);                            \
    }

__global__ __launch_bounds__(256, 2) void fused_kernel(
        const float* __restrict__ x,
        const short* __restrict__ whi, const short* __restrict__ wlo,
        const float* __restrict__ bias,
        const short* __restrict__ ehi, const short* __restrict__ elo,
        const float* __restrict__ nhcc,
        const float* __restrict__ embed, float* __restrict__ out,
        int* __restrict__ hist, float* __restrict__ lossacc) {
    // LDS plan (36608 B total, region reuse is sequential + barrier-guarded):
    //   xw   [4][32][66] f32 @ 0      (33792)  phase-1 transpose (wave-private)
    //   M1   [64][68] f32    @ 0      (17408)  merge buf (reuses xw)
    //   M2   [64][68] f32    @ 17408  (17408)
    //   H    [2][8192] short @ 0      (32768)  h image hi|lo (reuses M1/M2)
    //   tile [64][69] f32    @ 0      (17664)  gather (reuses H)
    //   qsm/vtmp/itmp        @ 34816  (1792)
    __shared__ __align__(16) char smem[36608];
    float* xw   = (float*)smem;
    float* M1   = (float*)smem;
    float* M2   = (float*)(smem + 17408);
    short* H    = (short*)smem;
    float* tile = (float*)smem;
    int*   qsm  = (int*)(smem + 34816);
    float* vtmp = (float*)(smem + 35072);
    int*   itmp = (int*)(smem + 35840);

    const int tid = threadIdx.x;
    const int wave = tid >> 6, lane = tid & 63;
    const int row16 = lane & 15, quad = lane >> 4;
    const int blk = blockIdx.x;              // 1024 blocks, 64 t each
    const int b  = blk >> 6;
    const int t0 = (blk & 63) * 64;
    const float* xr = x + (size_t)b * C_ * T_ + t0;
    float* wl = xw + wave * (32 * 66);

    const int c_row = lane >> 4;             // 0..3
    const int c_t4  = (lane & 15) * 4;       // 16 lanes x float4 = 256-B segment
    const int cbase = wave * 128;            // 4-way c-split

    // ---------------- Phase 1: projection (barrier-free loop) ----------------
    f32x4 acc[4][4];
#pragma unroll
    for (int rt = 0; rt < 4; ++rt)
#pragma unroll
        for (int et = 0; et < 4; ++et) acc[rt][et] = (f32x4){0.f, 0.f, 0.f, 0.f};

    float4 xn[8];
#pragma unroll
    for (int q = 0; q < 8; ++q)
        xn[q] = *(const float4*)(xr + (size_t)(cbase + q * 4 + c_row) * T_ + c_t4);

    for (int it = 0; it < 4; ++it) {
        const int c0 = cbase + it * 32;
#pragma unroll
        for (int q = 0; q < 8; ++q) {
            float* d = wl + (q * 4 + c_row) * 66 + c_t4;
            *(float2*)(d)     = make_float2(xn[q].x, xn[q].y);
            *(float2*)(d + 2) = make_float2(xn[q].z, xn[q].w);
        }
        if (it < 3) {
#pragma unroll
            for (int q = 0; q < 8; ++q)
                xn[q] = *(const float4*)(xr + (size_t)(c0 + 32 + q * 4 + c_row) * T_ + c_t4);
        }
#pragma unroll
        for (int rp = 0; rp < 2; ++rp) {
            short8 bh[2], bl[2];
#pragma unroll
            for (int rr = 0; rr < 2; ++rr) {
                const int rt = rp * 2 + rr;
#pragma unroll
                for (int j = 0; j < 8; ++j) {
                    float v = wl[(quad * 8 + j) * 66 + rt * 16 + row16];
                    HiLo r = split_rne(v);
                    bh[rr][j] = r.hi; bl[rr][j] = r.lo;
                }
            }
#pragma unroll
            for (int et = 0; et < 4; ++et) {
                size_t aoff = (size_t)(et * 16 + row16) * C_ + c0 + quad * 8;
                short8 ah = *(const short8*)(whi + aoff);
                short8 al = *(const short8*)(wlo + aoff);
#pragma unroll
                for (int rr = 0; rr < 2; ++rr) {
                    const int rt = rp * 2 + rr;
                    acc[rt][et] = __builtin_amdgcn_mfma_f32_16x16x32_bf16(ah, bh[rr], acc[rt][et], 0, 0, 0);
                    acc[rt][et] = __builtin_amdgcn_mfma_f32_16x16x32_bf16(al, bh[rr], acc[rt][et], 0, 0, 0);
                    acc[rt][et] = __builtin_amdgcn_mfma_f32_16x16x32_bf16(ah, bl[rr], acc[rt][et], 0, 0, 0);
                    acc[rt][et] = __builtin_amdgcn_mfma_f32_16x16x32_bf16(al, bl[rr], acc[rt][et], 0, 0, 0);
                }
            }
        }
    }

    // ---- tree-merge the 4 c-partials in f32 via LDS ----
    // D layout: t = rt*16 + row16, e = et*16 + quad*4 + r.
    __syncthreads();                         // xw dead
    if (wave == 1 || wave == 3) {
        float* Mx = (wave == 1) ? M1 : M2;
#pragma unroll
        for (int rt = 0; rt < 4; ++rt)
#pragma unroll
            for (int et = 0; et < 4; ++et)
#pragma unroll
                for (int r = 0; r < 4; ++r)
                    Mx[(et * 16 + quad * 4 + r) * 68 + rt * 16 + row16] = acc[rt][et][r];
    }
    __syncthreads();
    if (wave == 0 || wave == 2) {
        float* Mx = (wave == 0) ? M1 : M2;
#pragma unroll
        for (int rt = 0; rt < 4; ++rt)
#pragma unroll
            for (int et = 0; et < 4; ++et)
#pragma unroll
                for (int r = 0; r < 4; ++r)
                    acc[rt][et][r] += Mx[(et * 16 + quad * 4 + r) * 68 + rt * 16 + row16];
    }
    __syncthreads();
    if (wave == 2) {
#pragma unroll
        for (int rt = 0; rt < 4; ++rt)
#pragma unroll
            for (int et = 0; et < 4; ++et)
#pragma unroll
                for (int r = 0; r < 4; ++r)
                    M1[(et * 16 + quad * 4 + r) * 68 + rt * 16 + row16] = acc[rt][et][r];
    }
    __syncthreads();
    if (wave == 0) {
        float hh = 0.f;
#pragma unroll
        for (int rt = 0; rt < 4; ++rt) {
#pragma unroll
            for (int et = 0; et < 4; ++et) {
                float4 bv = *(const float4*)(bias + et * 16 + quad * 4);
                f32x4 a = acc[rt][et];
#pragma unroll
                for (int r = 0; r < 4; ++r)
                    a[r] += M1[(et * 16 + quad * 4 + r) * 68 + rt * 16 + row16];
                a[0] += bv.x; a[1] += bv.y; a[2] += bv.z; a[3] += bv.w;
                hh = fmaf(a[0], a[0], hh); hh = fmaf(a[1], a[1], hh);
                hh = fmaf(a[2], a[2], hh); hh = fmaf(a[3], a[3], hh);
                short4v hv, lv;
#pragma unroll
                for (int r = 0; r < 4; ++r) {
                    HiLo sp = split_rne(a[r]);
                    hv[r] = sp.hi; lv[r] = sp.lo;
                }
                // A-frag tiled slot (w2 = rt), matches the phase-2 reader.
                const int ks = et >> 1;
                const int qe = (et & 1) * 2 + (quad >> 1);
                const int j0 = (quad & 1) * 4;
                const int sl = ((rt * 2 + ks) * 64 + qe * 16 + row16) * 8 + j0;
                *(short4v*)(H + sl) = hv;
                *(short4v*)(H + 8192 + sl) = lv;
            }
        }
#pragma unroll
        for (int m = 1; m < 64; m <<= 1) hh += __shfl_xor(hh, m, 64);
        if (lane == 0) atomicAdd(lossacc, hh);
    }
    __syncthreads();                         // H ready

    // ---------------- Phase 2: VQ scan (kh = wave) ----------------
    const int kh = wave;
    short8 a_hi[4][2], a_lo[4][2];
#pragma unroll
    for (int rt = 0; rt < 4; ++rt)
#pragma unroll
        for (int ks = 0; ks < 2; ++ks) {
            const int sl = ((rt * 2 + ks) * 64 + lane) * 8;
            a_hi[rt][ks] = *(const short8*)(H + sl);
            a_lo[rt][ks] = *(const short8*)(H + 8192 + sl);
        }

    float vmax[4][4];
    int   vidx[4][4];
#pragma unroll
    for (int rt = 0; rt < 4; ++rt)
#pragma unroll
        for (int rg = 0; rg < 4; ++rg) { vmax[rt][rg] = -3.4e38f; vidx[rt][rg] = 0; }

    short8 pAh0, pAh1, pAl0, pAl1;
    short8 pBh0, pBh1, pBl0, pBl1;
    VQ_LOAD(pAh0, pAh1, pAl0, pAl1, 0);
    for (int s = 0; s < 32; s += 2) {
        VQ_LOAD(pBh0, pBh1, pBl0, pBl1, s + 1);
        VQ_STEP(pAh0, pAh1, pAl0, pAl1, s);
        if (s + 2 < 32) VQ_LOAD(pAh0, pAh1, pAl0, pAl1, s + 2);
        VQ_STEP(pBh0, pBh1, pBl0, pBl1, s + 1);
    }

    // 16-lane k-reduce (tie -> lowest idx), then 4-way kh merge via LDS.
    float s_loss = 0.f;
#pragma unroll
    for (int rt = 0; rt < 4; ++rt)
#pragma unroll
        for (int rg = 0; rg < 4; ++rg) {
            float v = vmax[rt][rg];
            int ix = vidx[rt][rg];
#pragma unroll
            for (int m = 1; m < 16; m <<= 1) {
                float ov = __shfl_xor(v, m, 64);
                int   oi = __shfl_xor(ix, m, 64);
                if (ov > v || (ov == v && oi < ix)) { v = ov; ix = oi; }
            }
            vmax[rt][rg] = v; vidx[rt][rg] = ix;
        }
    if (kh >= 1 && row16 == 0) {
#pragma unroll
        for (int rt = 0; rt < 4; ++rt)
#pragma unroll
            for (int rg = 0; rg < 4; ++rg) {
                const int row = rt * 16 + quad * 4 + rg;   // local 0..63
                vtmp[(kh - 1) * 64 + row] = vmax[rt][rg];
                itmp[(kh - 1) * 64 + row] = vidx[rt][rg];
            }
    }
    __syncthreads();
    if (kh == 0) {
        if (row16 == 0) {
#pragma unroll
            for (int rt = 0; rt < 4; ++rt)
#pragma unroll
                for (int rg = 0; rg < 4; ++rg) {
                    const int row = rt * 16 + quad * 4 + rg;
                    float v = vmax[rt][rg];
                    int ix = vidx[rt][rg];
#pragma unroll
                    for (int p = 0; p < 3; ++p) {
                        const float ov = vtmp[p * 64 + row];
                        const int   oi = itmp[p * 64 + row];
                        if (ov > v || (ov == v && oi < ix)) { v = ov; ix = oi; }
                    }
                    qsm[row] = ix;
                    atomicAdd(&hist[ix], 1);
                    s_loss += v;
                }
        }
        s_loss += __shfl_xor(s_loss, 16, 64);
        s_loss += __shfl_xor(s_loss, 32, 64);
        if (lane == 0) atomicAdd(lossacc, -2.f * s_loss);
    }
    __syncthreads();                         // qsm ready; H dead -> tile reuse OK

    // ---------------- Fused gather + transpose (64 rows) ----------------
    {
        const int r = tid >> 2, piece = tid & 3;
        const float* src = embed + (size_t)qsm[r] * 64 + piece * 16;
        float* dst = tile + r * 69 + piece * 16;
#pragma unroll
        for (int j = 0; j < 4; ++j)
            *(float4*)(dst + j * 4) = *(const float4*)(src + j * 4);
    }
    __syncthreads();
    {
        const int tt = tid & 63;
        const int eo = tid >> 6;               // 0..3
        float* ob = out + ((size_t)b * 64) * T_ + t0;
#pragma unroll
        for (int j = 0; j < 16; ++j) {
            const int e = j * 4 + eo;
            ob[(size_t)e * T_ + tt] = tile[tt * 69 + e];
        }
    }
}

// ---------------------------------------------------------------------------
// Finalize: loss, kldiv constant, log-perplexity.
// ---------------------------------------------------------------------------
__global__ void finalize_kernel(const int* __restrict__ hist,
                                const float* __restrict__ lossacc,
                                float* __restrict__ out) {
    __shared__ float red[4];
    const int tid = threadIdx.x;
    float s = 0.f;
    for (int k = tid; k < K_; k += 256) {
        float p = (float)hist[k] * (1.f / 65536.f);
        s -= p * logf(p + 1e-10f);
    }
#pragma unroll
    for (int m = 1; m < 64; m <<= 1) s += __shfl_xor(s, m, 64);
    if ((tid & 63) == 0) red[tid >> 6] = s;
    __syncthreads();
    if (tid == 0) {
        float lp = red[0] + red[1] + red[2] + red[3];
        out[ZQ_ELEMS] = 0.25f * lossacc[0] / (float)ZQ_ELEMS;    // loss
        out[ZQ_ELEMS + 17] = lp;                                  // log_perplexity
    }
    if (tid < 16) out[ZQ_ELEMS + 1 + tid] = logf(2048.f) * 4096.f;  // kldiv_r
}

// ---------------------------------------------------------------------------
extern "C" void kernel_launch(void* const* d_in, const int* in_sizes, int n_in,
                              void* d_out, int out_size, void* d_ws, size_t ws_size,
                              hipStream_t stream) {
    const float* x      = (const float*)d_in[0];
    const float* proj_w = (const float*)d_in[1];
    const float* proj_b = (const float*)d_in[2];
    const float* embed  = (const float*)d_in[3];
    float* out = (float*)d_out;
    char* ws = (char*)d_ws;

    short* e_hi = (short*)(ws + WS_EHI);
    short* e_lo = (short*)(ws + WS_ELO);
    float* nhcc = (float*)(ws + WS_NHCC);
    short* w_hi = (short*)(ws + WS_WHI);
    short* w_lo = (short*)(ws + WS_WLO);
    int*   hist = (int*)(ws + WS_HIST);
    float* lossac = (float*)(ws + WS_LOSS);

    prep_kernel<<<96, 256, 0, stream>>>(embed, proj_w, e_hi, e_lo, nhcc,
                                        w_hi, w_lo, hist);
    fused_kernel<<<1024, 256, 0, stream>>>(x, w_hi, w_lo, proj_b,
                                           e_hi, e_lo, nhcc, embed, out,
                                           hist, lossac);
    finalize_kernel<<<1, 256, 0, stream>>>(hist, lossac, out);
}